// Round 11
// baseline (216.584 us; speedup 1.0000x reference)
//
#include <hip/hip_runtime.h>

#define NPTS 65536
#define CCH  32
#define DDIM 64
#define GVOX (DDIM*DDIM*DDIM)   // B=1 -> 262144 voxels
#define MAXTILES 4128           // >= 65536/16 + 27 (per-class padding)
#define NSLOT (MAXTILES*16)
#define NTHREADS 1024
#define NBLOCKS  256            // 1 block/CU (55.8 KB LDS), proven co-resident (r7/r9/r10)
#define TTOT (NTHREADS*NBLOCKS)

typedef _Float16 half8  __attribute__((ext_vector_type(8)));
typedef _Float16 half4v __attribute__((ext_vector_type(4)));
typedef float    floatx4 __attribute__((ext_vector_type(4)));

// P0 ranges: map | sorted | pcs | values->f16 | weights | zero rows | cnt+slot
#define P0N (GVOX/4 + NSLOT/4 + NSLOT/4 + (NPTS*CCH)/4 + 27*CCH*CCH + CCH + 27)

struct SharedC {
  _Float16 lw[27*CCH*CCH];   // 55296 B: all 27 taps' weights, lane-linear
  int tstart[28];
  int clsbase[27];
  int lcnt[27];
  int lbase[27];
};

// ---- monotonic spin grid-barrier (graph-capturable, bounded) ----
// r10 lesson: polling with atomicAdd(bar,0) is a device-scope RMW -> 256
// spinners form an RMW convoy on one cacheline (~30us/barrier). Arrival
// stays an RMW (256 total, pipelines fine); POLLING is a device-scope
// LOAD (concurrent, no serialization). threadfence = release/acquire.
__device__ __forceinline__ void gbar(int* bar, int target) {
  __syncthreads();
  if (threadIdx.x == 0) {
    __threadfence();
    atomicAdd(bar, 1);
    int guard = 1 << 24;
    while (__hip_atomic_load(bar, __ATOMIC_RELAXED, __HIP_MEMORY_SCOPE_AGENT) < target
           && --guard)
      __builtin_amdgcn_s_sleep(2);
    __threadfence();
  }
  __syncthreads();
}

// ---- conv phase (verified logic from mega3/megak) ----
// wave = 1 tile x 27 taps; batched map-gather -> srcs regs; grouped 9-wide
// A-prefetch; lane-linear LDS B-reads (conflict-free); setprio around MFMA.
template<int MODE>
__device__ void conv_phase(SharedC& sh,
    const _Float16* __restrict__ A, const int* __restrict__ map,
    const int* __restrict__ pcs, const int* __restrict__ sorted,
    const _Float16* __restrict__ WT, const float* __restrict__ bias,
    const float* __restrict__ mask, const float* __restrict__ resid,
    _Float16* __restrict__ hout, float* __restrict__ fout)
{
  for (int i = threadIdx.x; i < 3456; i += NTHREADS)
    ((half8*)sh.lw)[i] = ((const half8*)WT)[i];
  __syncthreads();

  const int wv   = threadIdx.x >> 6;       // 0..15, wave = 1 tile
  const int lane = threadIdx.x & 63;
  const int m = lane & 15, quad = lane >> 4;
  const int nt = sh.tstart[27];
  const float bi0 = bias[m], bi1 = bias[m+16];

  for (int tile = blockIdx.x*16 + wv; tile < nt; tile += NBLOCKS*16) {
    int scls = 0;
    for (int cc = 1; cc < 27; ++cc) if (tile >= sh.tstart[cc]) scls = cc;
    scls = __builtin_amdgcn_readfirstlane(scls);
    const int cz = scls/9, cy = (scls/3)%3, cx = scls%3;

    const int pc = pcs[tile*16 + m];       // slot-indexed packed coords
    const int bb = pc>>18, z = (pc>>12)&63, y = (pc>>6)&63, x = pc&63;
    const int linb = bb << 18;
    const int az[3] = { max(z-1,0)<<12, z<<12, min(z+1,DDIM-1)<<12 };
    const int ay[3] = { max(y-1,0)<<6,  y<<6,  min(y+1,DDIM-1)<<6 };
    const int ax[3] = { max(x-1,0),     x,     min(x+1,DDIM-1) };

    int srcs[27];                          // 27 independent gathers, 1 round trip
#pragma unroll
    for (int j = 0; j < 27; ++j) {
      const int jz = j/9, jy = (j/3)%3, jx = j%3;
      const int s = map[linb | az[jz] | ay[jy] | ax[jx]];
      srcs[j] = ((s < 0) ? NPTS : s) * CCH;   // empty voxel -> zero row
    }

    floatx4 acc0 = {0.f,0.f,0.f,0.f};
    floatx4 acc1 = {0.f,0.f,0.f,0.f};

#pragma unroll
    for (int g = 0; g < 3; ++g) {
      half8 av[9];
#pragma unroll
      for (int u = 0; u < 9; ++u)          // 9 independent A-gathers in flight
        av[u] = *(const half8*)(A + srcs[g*9 + u] + quad*8);
      __builtin_amdgcn_s_setprio(1);
#pragma unroll
      for (int u = 0; u < 9; ++u) {
        const int j = g*9 + u;
        const int jz = j/9, jy = (j/3)%3, jx = j%3;
        const int tz = (cz==1) ? (2-jz) : ((jz==1) ? 1 : ((cz==0) ? 0 : 2));
        const int ty = (cy==1) ? (2-jy) : ((jy==1) ? 1 : ((cy==0) ? 0 : 2));
        const int tx = (cx==1) ? (2-jx) : ((jx==1) ? 1 : ((cx==0) ? 0 : 2));
        const int t  = tz*9 + ty*3 + tx;
        const _Float16* wr = sh.lw + t*1024;  // lane l -> byte l*16, linear
        half8 b0 = *(const half8*)(wr + lane*8);
        half8 b1 = *(const half8*)(wr + 512 + lane*8);
        acc0 = __builtin_amdgcn_mfma_f32_16x16x32_f16(av[u], b0, acc0, 0, 0, 0);
        acc1 = __builtin_amdgcn_mfma_f32_16x16x32_f16(av[u], b1, acc1, 0, 0, 0);
      }
      __builtin_amdgcn_s_setprio(0);
    }

    // D layout: col(N=cout) = lane&15, row(M=point) = quad*4 + reg
#pragma unroll
    for (int reg = 0; reg < 4; ++reg) {
      const int r  = quad*4 + reg;
      const int pr = sorted[tile*16 + r];
      if (pr >= NPTS) continue;            // padded lane
      const float mk = mask[pr];
      float v0 = (acc0[reg] + mk*bi0) * mk;
      float v1 = (acc1[reg] + mk*bi1) * mk;
      if (MODE == 0) {
        v0 = fmaxf(v0, 0.f); v1 = fmaxf(v1, 0.f);
        hout[pr*CCH + m]      = (_Float16)v0;
        hout[pr*CCH + m + 16] = (_Float16)v1;
      } else {
        fout[pr*CCH + m]      = resid[pr*CCH + m]      + v0;
        fout[pr*CCH + m + 16] = resid[pr*CCH + m + 16] + v1;
      }
    }
  }
}

// ---- the fused persistent kernel (plain launch -> graph-captured & timed) ----
__global__ __launch_bounds__(1024, 4) void megak(
    const float* __restrict__ values, const int* __restrict__ idx,
    const float* __restrict__ maskv,
    const float* __restrict__ k1, const float* __restrict__ bias1,
    const float* __restrict__ k2, const float* __restrict__ bias2,
    int* __restrict__ map, int* __restrict__ sorted, int* __restrict__ pcs,
    int* __restrict__ cnt, int* __restrict__ slot,
    _Float16* __restrict__ valsh, _Float16* __restrict__ hh,
    _Float16* __restrict__ wt1, _Float16* __restrict__ wt2,
    float* __restrict__ out, int* bar)
{
  __shared__ SharedC sh;
  const int gtid = blockIdx.x*NTHREADS + threadIdx.x;

  // ---- P0: init + dtype conversion (grid-stride) ----
  for (int t0 = gtid; t0 < P0N; t0 += TTOT) {
    int tid = t0;
    if (tid < GVOX/4) { ((int4*)map)[tid] = make_int4(-1,-1,-1,-1); continue; }
    tid -= GVOX/4;
    if (tid < NSLOT/4) { ((int4*)sorted)[tid] = make_int4(NPTS,NPTS,NPTS,NPTS); continue; }
    tid -= NSLOT/4;
    if (tid < NSLOT/4) { ((int4*)pcs)[tid] = make_int4(0,0,0,0); continue; }
    tid -= NSLOT/4;
    if (tid < (NPTS*CCH)/4) {
      float4 v = ((const float4*)values)[tid];
      half4v h = { (_Float16)v.x, (_Float16)v.y, (_Float16)v.z, (_Float16)v.w };
      ((half4v*)valsh)[tid] = h; continue;
    }
    tid -= (NPTS*CCH)/4;
    if (tid < 27*CCH*CCH) {
      // (t,cin,cout) f32 -> lane-linear f16: o = t*1024 + h*512 + l*8 + i
      int t = tid/(CCH*CCH), r = tid%(CCH*CCH);
      int cin = r/CCH, cout = r%CCH;
      int h = cout >> 4, mm = cout & 15, q = cin >> 3, i = cin & 7;
      int o = t*1024 + h*512 + (q*16 + mm)*8 + i;
      wt1[o] = (_Float16)k1[tid]; wt2[o] = (_Float16)k2[tid]; continue;
    }
    tid -= 27*CCH*CCH;
    if (tid < CCH) { valsh[NPTS*CCH+tid] = (_Float16)0.f; hh[NPTS*CCH+tid] = (_Float16)0.f; continue; }
    tid -= CCH;
    if (tid < 27) { cnt[tid] = 0; slot[tid] = 0; continue; }
  }
  gbar(bar, NBLOCKS);

  // ---- P1: map + class histogram (pc/myc kept in registers) ----
  if (threadIdx.x < 27) sh.lcnt[threadIdx.x] = 0;
  __syncthreads();
  int myc = -1, mypc = 0;
  if (gtid < NPTS) {
    const int4 v = ((const int4*)idx)[gtid];
    const int b = v.x, z = v.y, y = v.z, x = v.w;
    map[((b*DDIM + z)*DDIM + y)*DDIM + x] = gtid;
    mypc = (b<<18) | (z<<12) | (y<<6) | x;
    const int cz = (z==0)?0:((z==DDIM-1)?2:1);
    const int cy = (y==0)?0:((y==DDIM-1)?2:1);
    const int cx = (x==0)?0:((x==DDIM-1)?2:1);
    myc = cz*9 + cy*3 + cx;
    atomicAdd(&sh.lcnt[myc], 1);
  }
  __syncthreads();
  if (threadIdx.x < 27 && sh.lcnt[threadIdx.x])
    atomicAdd(&cnt[threadIdx.x], sh.lcnt[threadIdx.x]);
  gbar(bar, 2*NBLOCKS);

  // ---- P2: per-block class scan (coherent atomic reads) + scatter ----
  if (threadIdx.x == 0) {
    int b = 0, tb = 0;
    for (int c = 0; c < 27; ++c) {
      const int cv = atomicAdd(&cnt[c], 0);   // device-coherent read (27 only)
      sh.clsbase[c] = b; sh.tstart[c] = tb;
      const int ntc = (cv + 15) >> 4;
      b += ntc << 4; tb += ntc;
    }
    sh.tstart[27] = tb;
  }
  if (threadIdx.x < 27) sh.lcnt[threadIdx.x] = 0;
  __syncthreads();
  int lrank = 0;
  if (gtid < NPTS) lrank = atomicAdd(&sh.lcnt[myc], 1);
  __syncthreads();
  if (threadIdx.x < 27)
    sh.lbase[threadIdx.x] = sh.lcnt[threadIdx.x] ? atomicAdd(&slot[threadIdx.x], sh.lcnt[threadIdx.x]) : 0;
  __syncthreads();
  if (gtid < NPTS) {
    const int s = sh.clsbase[myc] + sh.lbase[myc] + lrank;
    sorted[s] = gtid;
    pcs[s] = mypc;
  }
  gbar(bar, 3*NBLOCKS);

  // ---- P3: conv1 (relu) ----
  conv_phase<0>(sh, valsh, map, pcs, sorted, wt1, bias1, maskv, nullptr, hh, nullptr);
  gbar(bar, 4*NBLOCKS);

  // ---- P4: conv2 (+residual) ----
  conv_phase<1>(sh, hh, map, pcs, sorted, wt2, bias2, maskv, values, nullptr, out);
}

// ---------------- launch ----------------

extern "C" void kernel_launch(void* const* d_in, const int* in_sizes, int n_in,
                              void* d_out, int out_size, void* d_ws, size_t ws_size,
                              hipStream_t stream) {
  const float* values = (const float*)d_in[0];
  const int*   indices= (const int*)  d_in[1];
  const float* maskv  = (const float*)d_in[2];
  const float* kern1  = (const float*)d_in[3];
  const float* bias1  = (const float*)d_in[4];
  const float* kern2  = (const float*)d_in[5];
  const float* bias2  = (const float*)d_in[6];
  float* out = (float*)d_out;

  char* ws = (char*)d_ws;
  size_t off = 0;
  auto alloc = [&](size_t bytes) { void* p = ws + off; off = (off + bytes + 255) & ~(size_t)255; return p; };
  int*      map     = (int*)     alloc(GVOX*4);                 // 1 MB
  int*      sorted  = (int*)     alloc(NSLOT*4);
  int*      pcs     = (int*)     alloc(NSLOT*4);
  int*      cnt     = (int*)     alloc(27*4);
  int*      slot    = (int*)     alloc(27*4);
  int*      bar     = (int*)     alloc(256);                    // spin-barrier counter
  _Float16* valsh   = (_Float16*)alloc((NPTS+1)*CCH*2);         // 4 MB
  _Float16* hh      = (_Float16*)alloc((NPTS+1)*CCH*2);         // 4 MB
  _Float16* wt1     = (_Float16*)alloc(27*CCH*CCH*2);
  _Float16* wt2     = (_Float16*)alloc(27*CCH*CCH*2);

  hipMemsetAsync(bar, 0, 4, stream);
  megak<<<NBLOCKS, NTHREADS, 0, stream>>>(
      values, indices, maskv, kern1, bias1, kern2, bias2,
      map, sorted, pcs, cnt, slot, valsh, hh, wt1, wt2, out, bar);
}

// Round 12
// 132.806 us; speedup vs baseline: 1.6308x; 1.6308x over previous
//
#include <hip/hip_runtime.h>

#define NPTS 65536
#define CCH  32
#define DDIM 64
#define GVOX (DDIM*DDIM*DDIM)   // B=1 -> 262144 voxels
#define MAXTILES 4128           // >= 65536/16 + 27 (per-class padding)
#define NSLOT (MAXTILES*16)

typedef _Float16 half8  __attribute__((ext_vector_type(8)));
typedef _Float16 half4v __attribute__((ext_vector_type(4)));
typedef float    floatx4 __attribute__((ext_vector_type(4)));

// ---------------- prep0: init + dtype conversion (one launch) ----------------
// ranges: map | sorted | pcs | values->f16 | weight transpose(lane-linear) | zero rows | counters
__global__ __launch_bounds__(256) void k_prep0(
    int* __restrict__ map, int* __restrict__ sorted, int* __restrict__ pcs,
    const float* __restrict__ values, _Float16* __restrict__ valsh,
    const float* __restrict__ k1, const float* __restrict__ k2,
    _Float16* __restrict__ w1, _Float16* __restrict__ w2,
    _Float16* __restrict__ hh, int* __restrict__ pcoord,
    int* __restrict__ cnt, int* __restrict__ slot)
{
  int tid = blockIdx.x * 256 + threadIdx.x;
  if (tid < GVOX/4) { ((int4*)map)[tid] = make_int4(-1,-1,-1,-1); return; }
  tid -= GVOX/4;
  if (tid < NSLOT) { sorted[tid] = NPTS; return; }
  tid -= NSLOT;
  if (tid < NSLOT) { pcs[tid] = 0; return; }
  tid -= NSLOT;
  if (tid < (NPTS*CCH)/4) {
    float4 v = ((const float4*)values)[tid];
    half4v h = { (_Float16)v.x, (_Float16)v.y, (_Float16)v.z, (_Float16)v.w };
    ((half4v*)valsh)[tid] = h; return;
  }
  tid -= (NPTS*CCH)/4;
  if (tid < 27*CCH*CCH) {
    // (t,cin,cout) f32 -> lane-linear f16 layout:
    // chunk for MFMA-lane l=(q*16+m) of half h=(cout>>4) at t*1024 + h*512 + l*8 + i
    int t = tid/(CCH*CCH), r = tid%(CCH*CCH);
    int cin = r/CCH, cout = r%CCH;
    int h = cout >> 4, mm = cout & 15, q = cin >> 3, i = cin & 7;
    int o = t*1024 + h*512 + (q*16 + mm)*8 + i;
    w1[o] = (_Float16)k1[tid]; w2[o] = (_Float16)k2[tid]; return;
  }
  tid -= 27*CCH*CCH;
  if (tid < CCH) { valsh[NPTS*CCH+tid] = (_Float16)0.f; hh[NPTS*CCH+tid] = (_Float16)0.f; return; }
  tid -= CCH;
  if (tid < 27) { cnt[tid] = 0; slot[tid] = 0; return; }
  tid -= 27;
  if (tid == 0) pcoord[NPTS] = 0;
}
#define PREP0_THREADS (GVOX/4 + NSLOT + NSLOT + (NPTS*CCH)/4 + 27*CCH*CCH + CCH + 27 + 1)

// ---------------- prep1: map + pcoord + class histogram ----------------
__global__ __launch_bounds__(256) void k_prep1(const int* __restrict__ idx,
                                               int* __restrict__ map,
                                               int* __restrict__ pcoord,
                                               int* __restrict__ cls,
                                               int* __restrict__ cnt)
{
  __shared__ int lcnt[27];
  if (threadIdx.x < 27) lcnt[threadIdx.x] = 0;
  __syncthreads();
  const int n = blockIdx.x*256 + threadIdx.x;
  const int4 v = ((const int4*)idx)[n];
  const int b = v.x, z = v.y, y = v.z, x = v.w;
  map[((b*DDIM + z)*DDIM + y)*DDIM + x] = n;
  pcoord[n] = (b<<18) | (z<<12) | (y<<6) | x;
  const int cz = (z==0)?0:((z==DDIM-1)?2:1);
  const int cy = (y==0)?0:((y==DDIM-1)?2:1);
  const int cx = (x==0)?0:((x==DDIM-1)?2:1);
  const int c = cz*9 + cy*3 + cx;
  cls[n] = c;
  atomicAdd(&lcnt[c], 1);
  __syncthreads();
  if (threadIdx.x < 27 && lcnt[threadIdx.x]) atomicAdd(&cnt[threadIdx.x], lcnt[threadIdx.x]);
}

// ---------------- prep3: per-block 27-class scan + scatter (+pcs) + tileclass
__global__ __launch_bounds__(256) void k_prep3(const int* __restrict__ cls,
                                               const int* __restrict__ cnt,
                                               int* __restrict__ slot,
                                               const int* __restrict__ pcoord,
                                               int* __restrict__ sorted,
                                               int* __restrict__ pcs,
                                               int* __restrict__ tileclass,
                                               int* __restrict__ ntiles)
{
  __shared__ int s_clsbase[27];
  __shared__ int s_tstart[28];
  if (threadIdx.x == 0) {
    int b = 0, tb = 0;
#pragma unroll
    for (int c = 0; c < 27; ++c) {
      s_clsbase[c] = b; s_tstart[c] = tb;
      const int ntc = (cnt[c] + 15) >> 4;
      b += ntc << 4; tb += ntc;
    }
    s_tstart[27] = tb;
    if (blockIdx.x == 0) *ntiles = tb;
  }
  __syncthreads();

  if (blockIdx.x < NPTS/256) {
    __shared__ int lcnt[27], lbase[27];
    if (threadIdx.x < 27) lcnt[threadIdx.x] = 0;
    __syncthreads();
    const int n = blockIdx.x*256 + threadIdx.x;
    const int c = cls[n];
    const int lrank = atomicAdd(&lcnt[c], 1);
    __syncthreads();
    if (threadIdx.x < 27)
      lbase[threadIdx.x] = lcnt[threadIdx.x] ? atomicAdd(&slot[threadIdx.x], lcnt[threadIdx.x]) : 0;
    __syncthreads();
    const int s = s_clsbase[c] + lbase[c] + lrank;
    sorted[s] = n;
    pcs[s] = pcoord[n];
  } else {
    const int i = (blockIdx.x - NPTS/256)*256 + threadIdx.x;
    if (i >= MAXTILES) return;
    const int nt = s_tstart[27];
    int c = 13;
    if (i < nt) {
      for (int cc = 0; cc < 27; ++cc)
        if (i >= s_tstart[cc] && i < s_tstart[cc+1]) { c = cc; break; }
    }
    tileclass[i] = c;
  }
}

// ---------------- conv: MODE 0 gathers map & WRITES nbr; MODE 1 reads nbr ---
// Grouped 9-wide A-prefetch + lane-linear LDS B-reads (conflict-free).
template<int MODE>
__global__ __launch_bounds__(512, 4) void conv_mfma(
    const _Float16* __restrict__ A,        // (NPTS+1) x 32 f16, row NPTS = zeros
    const int* __restrict__ map,
    const int* __restrict__ pcs,           // slot-indexed packed coords
    int* __restrict__ nbr,                 // MODE0: write; MODE1: read
    const int* __restrict__ sorted,
    const int* __restrict__ tileclass,
    const int* __restrict__ ntp,
    const _Float16* __restrict__ WT,       // 27 x 1024 f16, lane-linear layout
    const float* __restrict__ bias,
    const float* __restrict__ mask,
    const float* __restrict__ resid,
    _Float16* __restrict__ hout,
    float* __restrict__ fout)
{
  __shared__ _Float16 lw[27*CCH*CCH];      // 55296 B, linear copy of WT
  for (int i = threadIdx.x; i < 3456; i += 512)
    ((half8*)lw)[i] = ((const half8*)WT)[i];
  __syncthreads();

  const int wv   = threadIdx.x >> 6;       // 0..7, wave = 1 tile
  const int tile = blockIdx.x*8 + wv;
  const int lane = threadIdx.x & 63;
  const int m = lane & 15, quad = lane >> 4;
  if (tile >= *ntp) return;

  const int scls = __builtin_amdgcn_readfirstlane(tileclass[tile]);
  const int cz = scls/9, cy = (scls/3)%3, cx = scls%3;
  const int tb = tile*432;

  int srcs[27];
  if (MODE == 0) {
    // batched 27-wide independent map gather (one L2 round trip, r9-verified)
    const int pc = pcs[tile*16 + m];
    const int bb = pc>>18, z = (pc>>12)&63, y = (pc>>6)&63, x = pc&63;
    const int linb = bb << 18;
    const int az[3] = { max(z-1,0)<<12, z<<12, min(z+1,DDIM-1)<<12 };
    const int ay[3] = { max(y-1,0)<<6,  y<<6,  min(y+1,DDIM-1)<<6 };
    const int ax[3] = { max(x-1,0),     x,     min(x+1,DDIM-1) };
#pragma unroll
    for (int j = 0; j < 27; ++j) {
      const int jz = j/9, jy = (j/3)%3, jx = j%3;
      const int s = map[linb | az[jz] | ay[jy] | ax[jx]];
      srcs[j] = ((s < 0) ? NPTS : s) * CCH;   // empty voxel -> zero row
    }
    if (quad == 0) {                       // persist for conv2 (432 B x 16 lanes)
#pragma unroll
      for (int j = 0; j < 27; ++j) nbr[tb + j*16 + m] = srcs[j];
    }
  } else {
    // contiguous 1.7KB block, 27 independent 1-line loads
#pragma unroll
    for (int j = 0; j < 27; ++j) srcs[j] = nbr[tb + j*16 + m];
  }

  floatx4 acc0 = {0.f,0.f,0.f,0.f};
  floatx4 acc1 = {0.f,0.f,0.f,0.f};

#pragma unroll
  for (int g = 0; g < 3; ++g) {
    half8 av[9];
#pragma unroll
    for (int u = 0; u < 9; ++u)            // 9 independent gathers in flight
      av[u] = *(const half8*)(A + srcs[g*9 + u] + quad*8);
#pragma unroll
    for (int u = 0; u < 9; ++u) {
      const int j = g*9 + u;
      const int jz = j/9, jy = (j/3)%3, jx = j%3;
      const int tz = (cz==1) ? (2-jz) : ((jz==1) ? 1 : ((cz==0) ? 0 : 2));
      const int ty = (cy==1) ? (2-jy) : ((jy==1) ? 1 : ((cy==0) ? 0 : 2));
      const int tx = (cx==1) ? (2-jx) : ((jx==1) ? 1 : ((cx==0) ? 0 : 2));
      const int t  = tz*9 + ty*3 + tx;
      const _Float16* wr = lw + t*1024;    // lane-linear: lane l -> byte l*16
      half8 b0 = *(const half8*)(wr + lane*8);
      half8 b1 = *(const half8*)(wr + 512 + lane*8);
      acc0 = __builtin_amdgcn_mfma_f32_16x16x32_f16(av[u], b0, acc0, 0, 0, 0);
      acc1 = __builtin_amdgcn_mfma_f32_16x16x32_f16(av[u], b1, acc1, 0, 0, 0);
    }
  }

  // D layout: col(N=cout) = lane&15, row(M=point) = quad*4 + reg
  const float bi0 = bias[m], bi1 = bias[m+16];
#pragma unroll
  for (int reg = 0; reg < 4; ++reg) {
    const int r  = quad*4 + reg;
    const int pr = sorted[tile*16 + r];
    if (pr >= NPTS) continue;              // padded lane
    const float mk = mask[pr];
    float v0 = (acc0[reg] + mk*bi0) * mk;
    float v1 = (acc1[reg] + mk*bi1) * mk;
    if (MODE == 0) {
      v0 = fmaxf(v0, 0.f); v1 = fmaxf(v1, 0.f);
      hout[pr*CCH + m]      = (_Float16)v0;
      hout[pr*CCH + m + 16] = (_Float16)v1;
    } else {
      fout[pr*CCH + m]      = resid[pr*CCH + m]      + v0;
      fout[pr*CCH + m + 16] = resid[pr*CCH + m + 16] + v1;
    }
  }
}

// ---------------- launch (5 dispatches) ----------------

extern "C" void kernel_launch(void* const* d_in, const int* in_sizes, int n_in,
                              void* d_out, int out_size, void* d_ws, size_t ws_size,
                              hipStream_t stream) {
  const float* values = (const float*)d_in[0];
  const int*   indices= (const int*)  d_in[1];
  const float* maskv  = (const float*)d_in[2];
  const float* kern1  = (const float*)d_in[3];
  const float* bias1  = (const float*)d_in[4];
  const float* kern2  = (const float*)d_in[5];
  const float* bias2  = (const float*)d_in[6];
  float* out = (float*)d_out;

  char* ws = (char*)d_ws;
  size_t off = 0;
  auto alloc = [&](size_t bytes) { void* p = ws + off; off = (off + bytes + 255) & ~(size_t)255; return p; };
  int*      map      = (int*)     alloc(GVOX*4);            // 1 MB
  int*      pcoord   = (int*)     alloc((NPTS+1)*4);
  int*      cls      = (int*)     alloc(NPTS*4);
  int*      sorted   = (int*)     alloc(NSLOT*4);
  int*      pcs      = (int*)     alloc(NSLOT*4);
  int*      tileclass= (int*)     alloc(MAXTILES*4);
  int*      nbr      = (int*)     alloc((size_t)MAXTILES*432*4);  // ~7 MB
  int*      cnt      = (int*)     alloc(27*4);
  int*      slot     = (int*)     alloc(27*4);
  int*      ntiles   = (int*)     alloc(4);
  _Float16* valsh    = (_Float16*)alloc((NPTS+1)*CCH*2);    // 4 MB
  _Float16* hh       = (_Float16*)alloc((NPTS+1)*CCH*2);    // 4 MB
  _Float16* wt1      = (_Float16*)alloc(27*CCH*CCH*2);
  _Float16* wt2      = (_Float16*)alloc(27*CCH*CCH*2);

  k_prep0<<<(PREP0_THREADS + 255)/256, 256, 0, stream>>>(
      map, sorted, pcs, values, valsh, kern1, kern2, wt1, wt2, hh, pcoord, cnt, slot);
  k_prep1<<<NPTS/256, 256, 0, stream>>>(indices, map, pcoord, cls, cnt);
  k_prep3<<<NPTS/256 + (MAXTILES+255)/256, 256, 0, stream>>>(
      cls, cnt, slot, pcoord, sorted, pcs, tileclass, ntiles);

  conv_mfma<0><<<(MAXTILES + 7)/8, 512, 0, stream>>>(
      valsh, map, pcs, nbr, sorted, tileclass, ntiles,
      wt1, bias1, maskv, nullptr, hh, nullptr);
  conv_mfma<1><<<(MAXTILES + 7)/8, 512, 0, stream>>>(
      hh, map, pcs, nbr, sorted, tileclass, ntiles,
      wt2, bias2, maskv, values, nullptr, out);
}

// Round 15
// 130.848 us; speedup vs baseline: 1.6552x; 1.0150x over previous
//
#include <hip/hip_runtime.h>

#define NPTS 65536
#define CCH  32
#define DDIM 64
#define GVOX (DDIM*DDIM*DDIM)   // B=1 -> 262144 voxels
#define MAXTILES 4128           // >= 65536/16 + 27 (per-class padding)
#define NSLOT (MAXTILES*16)

typedef _Float16 half8  __attribute__((ext_vector_type(8)));
typedef _Float16 half4v __attribute__((ext_vector_type(4)));
typedef float    floatx4 __attribute__((ext_vector_type(4)));

// ---------------- prep0: init + dtype conversion (one launch) ----------------
// ranges: map | sorted | pcs | values->f16 | weight transpose(lane-linear) | zero rows | counters
__global__ __launch_bounds__(256) void k_prep0(
    int* __restrict__ map, int* __restrict__ sorted, int* __restrict__ pcs,
    const float* __restrict__ values, _Float16* __restrict__ valsh,
    const float* __restrict__ k1, const float* __restrict__ k2,
    _Float16* __restrict__ w1, _Float16* __restrict__ w2,
    _Float16* __restrict__ hh, int* __restrict__ pcoord,
    int* __restrict__ cnt, int* __restrict__ slot)
{
  int tid = blockIdx.x * 256 + threadIdx.x;
  if (tid < GVOX/4) { ((int4*)map)[tid] = make_int4(-1,-1,-1,-1); return; }
  tid -= GVOX/4;
  if (tid < NSLOT) { sorted[tid] = NPTS; return; }
  tid -= NSLOT;
  if (tid < NSLOT) { pcs[tid] = 0; return; }
  tid -= NSLOT;
  if (tid < (NPTS*CCH)/4) {
    float4 v = ((const float4*)values)[tid];
    half4v h = { (_Float16)v.x, (_Float16)v.y, (_Float16)v.z, (_Float16)v.w };
    ((half4v*)valsh)[tid] = h; return;
  }
  tid -= (NPTS*CCH)/4;
  if (tid < 27*CCH*CCH) {
    // (t,cin,cout) f32 -> lane-linear f16 layout:
    // chunk for MFMA-lane l=(q*16+m) of half h=(cout>>4) at t*1024 + h*512 + l*8 + i
    int t = tid/(CCH*CCH), r = tid%(CCH*CCH);
    int cin = r/CCH, cout = r%CCH;
    int h = cout >> 4, mm = cout & 15, q = cin >> 3, i = cin & 7;
    int o = t*1024 + h*512 + (q*16 + mm)*8 + i;
    w1[o] = (_Float16)k1[tid]; w2[o] = (_Float16)k2[tid]; return;
  }
  tid -= 27*CCH*CCH;
  if (tid < CCH) { valsh[NPTS*CCH+tid] = (_Float16)0.f; hh[NPTS*CCH+tid] = (_Float16)0.f; return; }
  tid -= CCH;
  if (tid < 27) { cnt[tid] = 0; slot[tid] = 0; return; }
  tid -= 27;
  if (tid == 0) pcoord[NPTS] = 0;
}
#define PREP0_THREADS (GVOX/4 + NSLOT + NSLOT + (NPTS*CCH)/4 + 27*CCH*CCH + CCH + 27 + 1)

// ---------------- prep1: map + pcoord + class histogram ----------------
__global__ __launch_bounds__(256) void k_prep1(const int* __restrict__ idx,
                                               int* __restrict__ map,
                                               int* __restrict__ pcoord,
                                               int* __restrict__ cls,
                                               int* __restrict__ cnt)
{
  __shared__ int lcnt[27];
  if (threadIdx.x < 27) lcnt[threadIdx.x] = 0;
  __syncthreads();
  const int n = blockIdx.x*256 + threadIdx.x;
  const int4 v = ((const int4*)idx)[n];
  const int b = v.x, z = v.y, y = v.z, x = v.w;
  map[((b*DDIM + z)*DDIM + y)*DDIM + x] = n;
  pcoord[n] = (b<<18) | (z<<12) | (y<<6) | x;
  const int cz = (z==0)?0:((z==DDIM-1)?2:1);
  const int cy = (y==0)?0:((y==DDIM-1)?2:1);
  const int cx = (x==0)?0:((x==DDIM-1)?2:1);
  const int c = cz*9 + cy*3 + cx;
  cls[n] = c;
  atomicAdd(&lcnt[c], 1);
  __syncthreads();
  if (threadIdx.x < 27 && lcnt[threadIdx.x]) atomicAdd(&cnt[threadIdx.x], lcnt[threadIdx.x]);
}

// ---------------- prep3: per-block 27-class scan + scatter (+pcs) + tileclass
__global__ __launch_bounds__(256) void k_prep3(const int* __restrict__ cls,
                                               const int* __restrict__ cnt,
                                               int* __restrict__ slot,
                                               const int* __restrict__ pcoord,
                                               int* __restrict__ sorted,
                                               int* __restrict__ pcs,
                                               int* __restrict__ tileclass,
                                               int* __restrict__ ntiles)
{
  __shared__ int s_clsbase[27];
  __shared__ int s_tstart[28];
  if (threadIdx.x == 0) {
    int b = 0, tb = 0;
#pragma unroll
    for (int c = 0; c < 27; ++c) {
      s_clsbase[c] = b; s_tstart[c] = tb;
      const int ntc = (cnt[c] + 15) >> 4;
      b += ntc << 4; tb += ntc;
    }
    s_tstart[27] = tb;
    if (blockIdx.x == 0) *ntiles = tb;
  }
  __syncthreads();

  if (blockIdx.x < NPTS/256) {
    __shared__ int lcnt[27], lbase[27];
    if (threadIdx.x < 27) lcnt[threadIdx.x] = 0;
    __syncthreads();
    const int n = blockIdx.x*256 + threadIdx.x;
    const int c = cls[n];
    const int lrank = atomicAdd(&lcnt[c], 1);
    __syncthreads();
    if (threadIdx.x < 27)
      lbase[threadIdx.x] = lcnt[threadIdx.x] ? atomicAdd(&slot[threadIdx.x], lcnt[threadIdx.x]) : 0;
    __syncthreads();
    const int s = s_clsbase[c] + lbase[c] + lrank;
    sorted[s] = n;
    pcs[s] = pcoord[n];
  } else {
    const int i = (blockIdx.x - NPTS/256)*256 + threadIdx.x;
    if (i >= MAXTILES) return;
    const int nt = s_tstart[27];
    int c = 13;
    if (i < nt) {
      for (int cc = 0; cc < 27; ++cc)
        if (i >= s_tstart[cc] && i < s_tstart[cc+1]) { c = cc; break; }
    }
    tileclass[i] = c;
  }
}

// ---------------- k_nbr: resolve all 27 neighbor A-offsets per slot ----------
// Massive-TLP latency hiding for the random map gathers (r12 lesson: folding
// this into conv1 loses ~6us). One 64B line per (tile, tap) in nbr.
__global__ __launch_bounds__(256) void k_nbr(const int* __restrict__ pcs,
                                             const int* __restrict__ map,
                                             int* __restrict__ nbr)
{
  const int tid = blockIdx.x*256 + threadIdx.x;
  if (tid >= MAXTILES*432) return;
  const int tile = tid/432, rem = tid%432;
  const int j = rem >> 4, m = rem & 15;
  const int pc = pcs[tile*16 + m];
  const int bb = pc>>18, z = (pc>>12)&63, y = (pc>>6)&63, x = pc&63;
  const int jz = j/9, jy = (j/3)%3, jx = j%3;
  const int nz = min(max(z + jz - 1, 0), DDIM-1);
  const int ny = min(max(y + jy - 1, 0), DDIM-1);
  const int nx = min(max(x + jx - 1, 0), DDIM-1);
  const int s = map[(bb<<18) | (nz<<12) | (ny<<6) | nx];
  nbr[tid] = ((s < 0) ? NPTS : s) * CCH;
}

// ---------------- conv: 2 tiles per wave (ILP) + lane-linear LDS weights ----
// r8-verified launch shape (512 thr, 55KB LDS, 1 blk/CU, 2 waves/SIMD).
// Per wave: 18 A-gathers in flight per group (2 tiles x 9) vs r8's 9 —
// doubles memory-level parallelism without changing occupancy.
// __launch_bounds__(512,2) raises VGPR cap to 256 (est ~170 live).
template<int MODE>
__global__ __launch_bounds__(512, 2) void conv_mfma(
    const _Float16* __restrict__ A,        // (NPTS+1) x 32 f16, row NPTS = zeros
    const int* __restrict__ nbr,
    const int* __restrict__ sorted,
    const int* __restrict__ tileclass,
    const int* __restrict__ ntp,
    const _Float16* __restrict__ WT,       // 27 x 1024 f16, lane-linear layout
    const float* __restrict__ bias,
    const float* __restrict__ mask,
    const float* __restrict__ resid,
    _Float16* __restrict__ hout,
    float* __restrict__ fout)
{
  __shared__ _Float16 lw[27*CCH*CCH];      // 55296 B, linear copy of WT
  for (int i = threadIdx.x; i < 3456; i += 512)
    ((half8*)lw)[i] = ((const half8*)WT)[i];
  __syncthreads();

  const int wv   = threadIdx.x >> 6;       // 0..7, wave = 2 tiles
  const int lane = threadIdx.x & 63;
  const int m = lane & 15, quad = lane >> 4;
  const int nt = *ntp;
  const int tA = blockIdx.x*16 + wv*2;
  if (tA >= nt) return;
  const bool actB = (tA + 1) < nt;
  const int tB = actB ? (tA + 1) : tA;     // duplicate tA when no B (writes guarded)

  const int sclsA = __builtin_amdgcn_readfirstlane(tileclass[tA]);
  const int sclsB = __builtin_amdgcn_readfirstlane(tileclass[tB]);
  const int czA = sclsA/9, cyA = (sclsA/3)%3, cxA = sclsA%3;
  const int czB = sclsB/9, cyB = (sclsB/3)%3, cxB = sclsB%3;

  // all 54 A-row offsets: two contiguous 1.7KB blocks, independent 1-line loads
  int srcsA[27], srcsB[27];
  const int tbA = tA*432, tbB = tB*432;
#pragma unroll
  for (int j = 0; j < 27; ++j) srcsA[j] = nbr[tbA + j*16 + m];
#pragma unroll
  for (int j = 0; j < 27; ++j) srcsB[j] = nbr[tbB + j*16 + m];

  floatx4 accA0 = {0.f,0.f,0.f,0.f}, accA1 = {0.f,0.f,0.f,0.f};
  floatx4 accB0 = {0.f,0.f,0.f,0.f}, accB1 = {0.f,0.f,0.f,0.f};

#pragma unroll
  for (int g = 0; g < 3; ++g) {
    half8 avA[9], avB[9];
#pragma unroll
    for (int u = 0; u < 9; ++u)            // 18 independent gathers in flight
      avA[u] = *(const half8*)(A + srcsA[g*9 + u] + quad*8);
#pragma unroll
    for (int u = 0; u < 9; ++u)
      avB[u] = *(const half8*)(A + srcsB[g*9 + u] + quad*8);
#pragma unroll
    for (int u = 0; u < 9; ++u) {
      const int j = g*9 + u;
      const int jz = j/9, jy = (j/3)%3, jx = j%3;
      {
        const int tz = (czA==1) ? (2-jz) : ((jz==1) ? 1 : ((czA==0) ? 0 : 2));
        const int ty = (cyA==1) ? (2-jy) : ((jy==1) ? 1 : ((cyA==0) ? 0 : 2));
        const int tx = (cxA==1) ? (2-jx) : ((jx==1) ? 1 : ((cxA==0) ? 0 : 2));
        const _Float16* wr = lw + (tz*9 + ty*3 + tx)*1024;  // lane l -> byte l*16
        half8 b0 = *(const half8*)(wr + lane*8);
        half8 b1 = *(const half8*)(wr + 512 + lane*8);
        accA0 = __builtin_amdgcn_mfma_f32_16x16x32_f16(avA[u], b0, accA0, 0, 0, 0);
        accA1 = __builtin_amdgcn_mfma_f32_16x16x32_f16(avA[u], b1, accA1, 0, 0, 0);
      }
      {
        const int tz = (czB==1) ? (2-jz) : ((jz==1) ? 1 : ((czB==0) ? 0 : 2));
        const int ty = (cyB==1) ? (2-jy) : ((jy==1) ? 1 : ((cyB==0) ? 0 : 2));
        const int tx = (cxB==1) ? (2-jx) : ((jx==1) ? 1 : ((cxB==0) ? 0 : 2));
        const _Float16* wr = lw + (tz*9 + ty*3 + tx)*1024;
        half8 b0 = *(const half8*)(wr + lane*8);
        half8 b1 = *(const half8*)(wr + 512 + lane*8);
        accB0 = __builtin_amdgcn_mfma_f32_16x16x32_f16(avB[u], b0, accB0, 0, 0, 0);
        accB1 = __builtin_amdgcn_mfma_f32_16x16x32_f16(avB[u], b1, accB1, 0, 0, 0);
      }
    }
  }

  // D layout: col(N=cout) = lane&15, row(M=point) = quad*4 + reg
  const float bi0 = bias[m], bi1 = bias[m+16];
#pragma unroll
  for (int reg = 0; reg < 4; ++reg) {
    const int r  = quad*4 + reg;
    {
      const int pr = sorted[tA*16 + r];
      if (pr < NPTS) {
        const float mk = mask[pr];
        float v0 = (accA0[reg] + mk*bi0) * mk;
        float v1 = (accA1[reg] + mk*bi1) * mk;
        if (MODE == 0) {
          v0 = fmaxf(v0, 0.f); v1 = fmaxf(v1, 0.f);
          hout[pr*CCH + m]      = (_Float16)v0;
          hout[pr*CCH + m + 16] = (_Float16)v1;
        } else {
          fout[pr*CCH + m]      = resid[pr*CCH + m]      + v0;
          fout[pr*CCH + m + 16] = resid[pr*CCH + m + 16] + v1;
        }
      }
    }
    if (actB) {
      const int pr = sorted[tB*16 + r];
      if (pr < NPTS) {
        const float mk = mask[pr];
        float v0 = (accB0[reg] + mk*bi0) * mk;
        float v1 = (accB1[reg] + mk*bi1) * mk;
        if (MODE == 0) {
          v0 = fmaxf(v0, 0.f); v1 = fmaxf(v1, 0.f);
          hout[pr*CCH + m]      = (_Float16)v0;
          hout[pr*CCH + m + 16] = (_Float16)v1;
        } else {
          fout[pr*CCH + m]      = resid[pr*CCH + m]      + v0;
          fout[pr*CCH + m + 16] = resid[pr*CCH + m + 16] + v1;
        }
      }
    }
  }
}

// ---------------- launch (6 dispatches) ----------------

extern "C" void kernel_launch(void* const* d_in, const int* in_sizes, int n_in,
                              void* d_out, int out_size, void* d_ws, size_t ws_size,
                              hipStream_t stream) {
  const float* values = (const float*)d_in[0];
  const int*   indices= (const int*)  d_in[1];
  const float* maskv  = (const float*)d_in[2];
  const float* kern1  = (const float*)d_in[3];
  const float* bias1  = (const float*)d_in[4];
  const float* kern2  = (const float*)d_in[5];
  const float* bias2  = (const float*)d_in[6];
  float* out = (float*)d_out;

  char* ws = (char*)d_ws;
  size_t off = 0;
  auto alloc = [&](size_t bytes) { void* p = ws + off; off = (off + bytes + 255) & ~(size_t)255; return p; };
  int*      map      = (int*)     alloc(GVOX*4);            // 1 MB
  int*      pcoord   = (int*)     alloc((NPTS+1)*4);
  int*      cls      = (int*)     alloc(NPTS*4);
  int*      sorted   = (int*)     alloc(NSLOT*4);
  int*      pcs      = (int*)     alloc(NSLOT*4);
  int*      tileclass= (int*)     alloc(MAXTILES*4);
  int*      nbr      = (int*)     alloc((size_t)MAXTILES*432*4);  // ~7 MB
  int*      cnt      = (int*)     alloc(27*4);
  int*      slot     = (int*)     alloc(27*4);
  int*      ntiles   = (int*)     alloc(4);
  _Float16* valsh    = (_Float16*)alloc((NPTS+1)*CCH*2);    // 4 MB
  _Float16* hh       = (_Float16*)alloc((NPTS+1)*CCH*2);    // 4 MB
  _Float16* wt1      = (_Float16*)alloc(27*CCH*CCH*2);
  _Float16* wt2      = (_Float16*)alloc(27*CCH*CCH*2);

  k_prep0<<<(PREP0_THREADS + 255)/256, 256, 0, stream>>>(
      map, sorted, pcs, values, valsh, kern1, kern2, wt1, wt2, hh, pcoord, cnt, slot);
  k_prep1<<<NPTS/256, 256, 0, stream>>>(indices, map, pcoord, cls, cnt);
  k_prep3<<<NPTS/256 + (MAXTILES+255)/256, 256, 0, stream>>>(
      cls, cnt, slot, pcoord, sorted, pcs, tileclass, ntiles);
  k_nbr<<<(MAXTILES*432 + 255)/256, 256, 0, stream>>>(pcs, map, nbr);

  conv_mfma<0><<<(MAXTILES + 15)/16, 512, 0, stream>>>(
      valsh, nbr, sorted, tileclass, ntiles,
      wt1, bias1, maskv, nullptr, hh, nullptr);
  conv_mfma<1><<<(MAXTILES + 15)/16, 512, 0, stream>>>(
      hh, nbr, sorted, tileclass, ntiles,
      wt2, bias2, maskv, values, nullptr, out);
}